// Round 1
// baseline (2967.763 us; speedup 1.0000x reference)
//
#include <hip/hip_runtime.h>

// WMSA fused kernel: one block per 7x7 window (4096 windows), 256 threads.
// All fp32. Phases: load -> QKV -> per-head attention -> out-proj + scatter.

__device__ __forceinline__ int swz(int t, int c) {
  // word index within one 49x192 part; XOR-swizzle 4-float groups by row
  // so stride-192 row reads across lanes are bank-conflict-free.
  return t * 192 + ((((c >> 2) ^ (t & 7)) << 2) | (c & 3));
}

__global__ __launch_bounds__(256, 1) void wmsa_kernel(
    const float* __restrict__ x,
    const float* __restrict__ Wqkv,
    const float* __restrict__ bqkv,
    const float* __restrict__ relpos,
    const float* __restrict__ Wout,
    const float* __restrict__ bout,
    float* __restrict__ out)
{
  __shared__ float s_qkv[3 * 49 * 192];  // q/k/v, swizzled rows      112,896 B
  __shared__ float s_P[49 * 192];        // xw (ph1) / attn out (ph2+) 37,632 B
  __shared__ float s_Q[2450];            // W slice (ph1/ph3) / scores  9,800 B

  const int tid = threadIdx.x;
  const int win = blockIdx.x;
  const int wi = win >> 6;   // window row [0,64)
  const int wj = win & 63;   // window col [0,64)

  // ---------------- Phase 0: load rolled window input ----------------
  for (int l = tid; l < 49 * 192; l += 256) {
    int t = l / 192;
    int c = l - t * 192;
    int hh = wi * 7 + t / 7 + 3;      if (hh >= 448) hh -= 448;
    int ww = wj * 7 + (t % 7) + 3;    if (ww >= 448) ww -= 448;
    s_P[l] = x[(hh * 448 + ww) * 192 + c];
  }
  __syncthreads();

  // ---------------- Phase 1: QKV projection M=49 N=576 K=192 ----------------
  {
    const int ot = tid % 36;
    const int tt = tid / 36;  // < 7 when tid < 252
    float acc[7][16];
#pragma unroll
    for (int i = 0; i < 7; ++i)
#pragma unroll
      for (int j = 0; j < 16; ++j) acc[i][j] = 0.0f;

    for (int kc = 0; kc < 48; ++kc) {
      // stage W_qkv[:, 4 K-columns] -> s_Q[o][cc]
      for (int l = tid; l < 2304; l += 256)
        s_Q[l] = Wqkv[(l >> 2) * 192 + (kc << 2) + (l & 3)];
      __syncthreads();
      if (tid < 252) {
        float4 xa[7];
#pragma unroll
        for (int i = 0; i < 7; ++i)
          xa[i] = *(const float4*)&s_P[(tt * 7 + i) * 192 + (kc << 2)];
#pragma unroll
        for (int j = 0; j < 16; ++j) {
          float4 w = *(const float4*)&s_Q[(j * 36 + ot) << 2];
#pragma unroll
          for (int i = 0; i < 7; ++i) {
            acc[i][j] += xa[i].x * w.x;
            acc[i][j] += xa[i].y * w.y;
            acc[i][j] += xa[i].z * w.z;
            acc[i][j] += xa[i].w * w.w;
          }
        }
      }
      __syncthreads();
    }
    if (tid < 252) {
#pragma unroll
      for (int j = 0; j < 16; ++j) {
        int o = j * 36 + ot;           // [0,576)
        int part = o / 192;            // 0=q 1=k 2=v
        int ch = o - part * 192;
        float b = bqkv[o];
#pragma unroll
        for (int i = 0; i < 7; ++i) {
          int t = tt * 7 + i;
          s_qkv[part * 9408 + swz(t, ch)] = acc[i][j] + b;
        }
      }
    }
  }
  __syncthreads();

  // ---------------- Phase 2: attention per head ----------------
  const float scale = 0.17677669529663687f;  // 32^-0.5
  for (int h = 0; h < 6; ++h) {
    // scores S[p][q] + rel-pos + gaussian prior + shift mask
    for (int idx = tid; idx < 2401; idx += 256) {
      int p = idx / 49;
      int q = idx - p * 49;
      float s = 0.0f;
#pragma unroll
      for (int dc = 0; dc < 8; ++dc) {
        float4 qa = *(const float4*)&s_qkv[swz(p, h * 32 + dc * 4)];
        float4 ka = *(const float4*)&s_qkv[9408 + swz(q, h * 32 + dc * 4)];
        s += qa.x * ka.x + qa.y * ka.y + qa.z * ka.z + qa.w * ka.w;
      }
      s *= scale;
      int pi = p / 7, pj = p - (p / 7) * 7;
      int qi = q / 7, qj = q - (q / 7) * 7;
      s += relpos[h * 169 + (pi - qi + 6) * 13 + (pj - qj + 6)];
      int d2 = (pi - qi) * (pi - qi) + (pj - qj) * (pj - qj);
      s += __expf((float)d2 * (-9.0f / 98.0f));
      bool m = ((wi == 63) && ((pi < 4) != (qi < 4))) ||
               ((wj == 63) && ((pj < 4) != (qj < 4)));
      s_Q[idx] = m ? -1e30f : s;
    }
    __syncthreads();
    // softmax per row (49 rows, one lane each)
    if (tid < 49) {
      float mx = -3.0e38f;
      for (int q = 0; q < 49; ++q) mx = fmaxf(mx, s_Q[tid * 49 + q]);
      float sum = 0.0f;
      for (int q = 0; q < 49; ++q) {
        float e = __expf(s_Q[tid * 49 + q] - mx);
        s_Q[tid * 49 + q] = e;
        sum += e;
      }
      float inv = 1.0f / sum;
      for (int q = 0; q < 49; ++q) s_Q[tid * 49 + q] *= inv;
    }
    __syncthreads();
    // PV: out[p][d] = sum_q probs[p][q] * v[q][h*32+d]
    for (int idx = tid; idx < 392; idx += 256) {  // 49 p x 8 d-chunks
      int p = idx >> 3;
      int dc = idx & 7;
      float ax = 0.f, ay = 0.f, az = 0.f, aw = 0.f;
      for (int q = 0; q < 49; ++q) {
        float pr = s_Q[p * 49 + q];
        float4 va = *(const float4*)&s_qkv[2 * 9408 + swz(q, h * 32 + dc * 4)];
        ax += pr * va.x; ay += pr * va.y; az += pr * va.z; aw += pr * va.w;
      }
      float4 r = {ax, ay, az, aw};
      *(float4*)&s_P[p * 192 + h * 32 + dc * 4] = r;
    }
    __syncthreads();
  }

  // ---------------- Phase 3: out projection M=49 N=192 K=192 + scatter ------
  {
    const int ot = tid % 24;
    const int tt = tid / 24;  // < 7 when tid < 168
    float acc[7][8];
#pragma unroll
    for (int i = 0; i < 7; ++i)
#pragma unroll
      for (int j = 0; j < 8; ++j) acc[i][j] = 0.0f;

    for (int kc = 0; kc < 48; ++kc) {
      for (int l = tid; l < 768; l += 256)
        s_Q[l] = Wout[(l >> 2) * 192 + (kc << 2) + (l & 3)];
      __syncthreads();
      if (tid < 168) {
        float4 xa[7];
#pragma unroll
        for (int i = 0; i < 7; ++i)
          xa[i] = *(const float4*)&s_P[(tt * 7 + i) * 192 + (kc << 2)];
#pragma unroll
        for (int j = 0; j < 8; ++j) {
          float4 w = *(const float4*)&s_Q[(j * 24 + ot) << 2];
#pragma unroll
          for (int i = 0; i < 7; ++i) {
            acc[i][j] += xa[i].x * w.x;
            acc[i][j] += xa[i].y * w.y;
            acc[i][j] += xa[i].z * w.z;
            acc[i][j] += xa[i].w * w.w;
          }
        }
      }
      __syncthreads();
    }
    if (tid < 168) {
      const int r = wi >> 4;     // RATIO slot
      const int w1i = wi & 15;
#pragma unroll
      for (int i = 0; i < 7; ++i) {
        int t = tt * 7 + i;
        int i2 = t / 7, j2 = t - (t / 7) * 7;
        int y = w1i * 7 + i2 + 3;   if (y >= 112) y -= 112;
        int xc = wj * 7 + j2 + 3;   if (xc >= 448) xc -= 448;
        size_t base = ((size_t)(y * 448 + xc)) * 768 + (size_t)(r * 192);
#pragma unroll
        for (int j = 0; j < 8; ++j) {
          int o = j * 24 + ot;
          out[base + o] = acc[i][j] + bout[o];
        }
      }
    }
  }
}

extern "C" void kernel_launch(void* const* d_in, const int* in_sizes, int n_in,
                              void* d_out, int out_size, void* d_ws, size_t ws_size,
                              hipStream_t stream) {
  const float* x      = (const float*)d_in[0];
  const float* Wqkv   = (const float*)d_in[1];
  const float* bqkv   = (const float*)d_in[2];
  const float* relpos = (const float*)d_in[3];
  const float* Wout   = (const float*)d_in[4];
  const float* bout   = (const float*)d_in[5];
  float* out = (float*)d_out;
  wmsa_kernel<<<4096, 256, 0, stream>>>(x, Wqkv, bqkv, relpos, Wout, bout, out);
}

// Round 2
// 576.635 us; speedup vs baseline: 5.1467x; 5.1467x over previous
//
#include <hip/hip_runtime.h>

typedef _Float16 f16;
typedef _Float16 f16x8 __attribute__((ext_vector_type(8)));
typedef _Float16 f16x4 __attribute__((ext_vector_type(4)));
typedef float f32x4 __attribute__((ext_vector_type(4)));

#define MFMA16(a, b, c) __builtin_amdgcn_mfma_f32_16x16x32_f16(a, b, c, 0, 0, 0)

// One block per 7x7 window. 256 threads = 4 waves.
// M = 64 rows (49 tokens + 15 zero-pad), MFMA 16x16x32 f16, fp32 accum.
__global__ __launch_bounds__(256, 1) void wmsa_mfma(
    const float* __restrict__ x,
    const float* __restrict__ Wqkv,
    const float* __restrict__ bqkv,
    const float* __restrict__ relpos,
    const float* __restrict__ Wout,
    const float* __restrict__ bout,
    float* __restrict__ out)
{
  // granule = 8 f16 = 16 B
  __shared__ __align__(16) f16 s_w[2320 * 8];      // W chunk, [g-plane(580)][n^g]   37120 B
  __shared__ __align__(16) f16 s_x[1536 * 8];      // x window / attn-out [64][24g]  24576 B
  __shared__ __align__(16) f16 s_qk[2 * 1536 * 8]; // q, k [64][24g] each            49152 B
  __shared__ __align__(16) f16 s_vT[1536 * 8];     // v^T [192ch][8g of tokens]      24576 B
  __shared__ __align__(16) f16 s_p[512 * 8];       // P [64][8g]                      8192 B
  __shared__ float s_add[6 * 169];                 // relpos + gaussian prior         4056 B

  const int tid = threadIdx.x;
  const int wi = blockIdx.x >> 6, wj = blockIdx.x & 63;
  const int wv = tid >> 6;          // wave id 0..3
  const int l = tid & 63;
  const int l15 = l & 15, lg = l >> 4;
  const f32x4 zero4 = {0.f, 0.f, 0.f, 0.f};

  // ---------------- Phase 0: stage x window (f16, swizzled) + add-tables ----
  for (int i = tid; i < 6 * 169; i += 256) {
    int h = i / 169, rem = i - h * 169;
    int di = rem / 13 - 6, dj = rem % 13 - 6;
    s_add[i] = relpos[i] + __expf((float)(di * di + dj * dj) * (-9.0f / 98.0f));
  }
  for (int gid = tid; gid < 1536; gid += 256) {
    int t = gid / 24, g = gid - t * 24;
    f16x8 v;
    if (t < 49) {
      int hh = wi * 7 + t / 7 + 3; if (hh >= 448) hh -= 448;
      int ww = wj * 7 + t % 7 + 3; if (ww >= 448) ww -= 448;
      const float4* src = (const float4*)(x + (size_t)(hh * 448 + ww) * 192 + g * 8);
      float4 u0 = src[0], u1 = src[1];
      v[0] = (f16)u0.x; v[1] = (f16)u0.y; v[2] = (f16)u0.z; v[3] = (f16)u0.w;
      v[4] = (f16)u1.x; v[5] = (f16)u1.y; v[6] = (f16)u1.z; v[7] = (f16)u1.w;
    } else {
#pragma unroll
      for (int e = 0; e < 8; ++e) v[e] = (f16)0.0f;
    }
    *(f16x8*)&s_x[(t * 24 + (g ^ (t & 7))) * 8] = v;
  }
  __syncthreads();

  // ---------------- Phase 1: QKV GEMM [64x192]@[192x576] --------------------
  // wave wv owns cols [144*wv, 144*wv+144) = 9 n-tiles, all 4 m-tiles.
  {
    f32x4 acc[4][9];
#pragma unroll
    for (int m = 0; m < 4; ++m)
#pragma unroll
      for (int j = 0; j < 9; ++j) acc[m][j] = zero4;

    for (int kc = 0; kc < 6; ++kc) {
      // stage W_qkv[:, kc*32 .. +32) as f16 granules: slot = g*580 + (n^g)
#pragma unroll
      for (int i = 0; i < 9; ++i) {
        int gid = tid + i * 256;          // 2304 granules
        int n = gid >> 2, g = gid & 3;
        const float4* src = (const float4*)(Wqkv + (size_t)n * 192 + kc * 32 + g * 8);
        float4 u0 = src[0], u1 = src[1];
        f16x8 v;
        v[0] = (f16)u0.x; v[1] = (f16)u0.y; v[2] = (f16)u0.z; v[3] = (f16)u0.w;
        v[4] = (f16)u1.x; v[5] = (f16)u1.y; v[6] = (f16)u1.z; v[7] = (f16)u1.w;
        *(f16x8*)&s_w[(g * 580 + (n ^ g)) * 8] = v;
      }
      __syncthreads();
      f16x8 a[4];
#pragma unroll
      for (int m = 0; m < 4; ++m) {
        int row = 16 * m + l15;
        a[m] = *(const f16x8*)&s_x[(row * 24 + ((kc * 4 + lg) ^ (row & 7))) * 8];
      }
#pragma unroll
      for (int j = 0; j < 9; ++j) {
        int n = wv * 144 + j * 16 + l15;
        f16x8 b = *(const f16x8*)&s_w[(lg * 580 + (n ^ lg)) * 8];
#pragma unroll
        for (int m = 0; m < 4; ++m) acc[m][j] = MFMA16(a[m], b, acc[m][j]);
      }
      __syncthreads();
    }

    // epilogue: +bias, write q/k (token-major) and v (transposed) as f16
#pragma unroll
    for (int j = 0; j < 9; ++j) {
      int c = wv * 144 + j * 16 + l15;
      float bias = bqkv[c];
      int part = c / 192;
      int ch = c - part * 192;
#pragma unroll
      for (int m = 0; m < 4; ++m) {
        int row0 = 16 * m + lg * 4;
        if (part < 2) {
#pragma unroll
          for (int r = 0; r < 4; ++r) {
            int row = row0 + r;
            s_qk[part * 12288 + (row * 24 + ((ch >> 3) ^ (row & 7))) * 8 + (ch & 7)] =
                (f16)(acc[m][j][r] + bias);
          }
        } else {
          f16x4 v;
#pragma unroll
          for (int r = 0; r < 4; ++r) v[r] = (f16)(acc[m][j][r] + bias);
          *(f16x4*)&s_vT[(ch * 8 + ((row0 >> 3) ^ (ch & 7))) * 8 + (row0 & 7)] = v;
        }
      }
    }
  }
  __syncthreads();

  // ---------------- Phase 2: attention, wave wv owns p-tile wv --------------
  const float scale = 0.17677669529663687f;
  for (int h = 0; h < 6; ++h) {
    // QK^T: S tile row 16wv.., all 4 q-tiles. K=32 = head dim, one MFMA each.
    int prow = 16 * wv + l15;
    f16x8 aq = *(const f16x8*)&s_qk[(prow * 24 + ((h * 4 + lg) ^ (prow & 7))) * 8];
    f32x4 sc[4];
#pragma unroll
    for (int jq = 0; jq < 4; ++jq) {
      int krow = 16 * jq + l15;
      f16x8 bk = *(const f16x8*)&s_qk[12288 + (krow * 24 + ((h * 4 + lg) ^ (krow & 7))) * 8];
      sc[jq] = MFMA16(aq, bk, zero4);
    }
    // in-register softmax. lane holds rows p = 16wv + lg*4 + r, cols q = 16jq + l15
    float sv[4][4];
    float m_r[4] = {-3.0e38f, -3.0e38f, -3.0e38f, -3.0e38f};
    int pbase = 16 * wv + lg * 4;
#pragma unroll
    for (int jq = 0; jq < 4; ++jq) {
      int q = 16 * jq + l15;
      int qi = q / 7, qj = q - qi * 7;
#pragma unroll
      for (int r = 0; r < 4; ++r) {
        int pp = pbase + r;
        float s = -1.0e30f;
        if (q < 49 && pp < 49) {
          int pi = pp / 7, pj = pp - pi * 7;
          s = sc[jq][r] * scale + s_add[h * 169 + (pi - qi + 6) * 13 + (pj - qj + 6)];
          bool msk = ((wi == 63) && ((pi < 4) != (qi < 4))) ||
                     ((wj == 63) && ((pj < 4) != (qj < 4)));
          if (msk) s = -1.0e30f;
        }
        sv[jq][r] = s;
        m_r[r] = fmaxf(m_r[r], s);
      }
    }
#pragma unroll
    for (int r = 0; r < 4; ++r)
#pragma unroll
      for (int d = 1; d < 16; d <<= 1)
        m_r[r] = fmaxf(m_r[r], __shfl_xor(m_r[r], d));
    float sum[4] = {0.f, 0.f, 0.f, 0.f};
#pragma unroll
    for (int jq = 0; jq < 4; ++jq)
#pragma unroll
      for (int r = 0; r < 4; ++r) {
        float e = __expf(sv[jq][r] - m_r[r]);
        sv[jq][r] = e;
        sum[r] += e;
      }
#pragma unroll
    for (int r = 0; r < 4; ++r) {
#pragma unroll
      for (int d = 1; d < 16; d <<= 1) sum[r] += __shfl_xor(sum[r], d);
      sum[r] = 1.0f / sum[r];
    }
#pragma unroll
    for (int jq = 0; jq < 4; ++jq) {
      int q = 16 * jq + l15;
#pragma unroll
      for (int r = 0; r < 4; ++r) {
        int row = pbase + r;
        s_p[(row * 8 + ((q >> 3) ^ (row & 7))) * 8 + (q & 7)] = (f16)(sv[jq][r] * sum[r]);
      }
    }
    __syncthreads();
    // PV: O rows 16wv.., 32 head channels (2 n-tiles), K = 64 tokens (2 steps)
    f32x4 o[2] = {zero4, zero4};
#pragma unroll
    for (int kq = 0; kq < 2; ++kq) {
      f16x8 ap = *(const f16x8*)&s_p[(prow * 8 + ((kq * 4 + lg) ^ (prow & 7))) * 8];
#pragma unroll
      for (int jn = 0; jn < 2; ++jn) {
        int ch = h * 32 + jn * 16 + l15;
        f16x8 bv = *(const f16x8*)&s_vT[(ch * 8 + ((kq * 4 + lg) ^ (ch & 7))) * 8];
        o[jn] = MFMA16(ap, bv, o[jn]);
      }
    }
#pragma unroll
    for (int jn = 0; jn < 2; ++jn) {
      int ch = h * 32 + jn * 16 + l15;
#pragma unroll
      for (int r = 0; r < 4; ++r) {
        int row = pbase + r;
        s_x[(row * 24 + ((ch >> 3) ^ (row & 7))) * 8 + (ch & 7)] = (f16)o[jn][r];
      }
    }
    __syncthreads();
  }

  // ---------------- Phase 3: out-proj [64x192]@[192x192] + scatter ----------
  {
    f32x4 acc3[4][3];
#pragma unroll
    for (int m = 0; m < 4; ++m)
#pragma unroll
      for (int j = 0; j < 3; ++j) acc3[m][j] = zero4;

    for (int kc = 0; kc < 6; ++kc) {
#pragma unroll
      for (int i = 0; i < 3; ++i) {
        int gid = tid + i * 256;          // 768 granules
        int n = gid >> 2, g = gid & 3;
        const float4* src = (const float4*)(Wout + (size_t)n * 192 + kc * 32 + g * 8);
        float4 u0 = src[0], u1 = src[1];
        f16x8 v;
        v[0] = (f16)u0.x; v[1] = (f16)u0.y; v[2] = (f16)u0.z; v[3] = (f16)u0.w;
        v[4] = (f16)u1.x; v[5] = (f16)u1.y; v[6] = (f16)u1.z; v[7] = (f16)u1.w;
        *(f16x8*)&s_w[(g * 196 + (n ^ g)) * 8] = v;
      }
      __syncthreads();
      f16x8 a[4];
#pragma unroll
      for (int m = 0; m < 4; ++m) {
        int row = 16 * m + l15;
        a[m] = *(const f16x8*)&s_x[(row * 24 + ((kc * 4 + lg) ^ (row & 7))) * 8];
      }
#pragma unroll
      for (int j = 0; j < 3; ++j) {
        int n = wv * 48 + j * 16 + l15;
        f16x8 b = *(const f16x8*)&s_w[(lg * 196 + (n ^ lg)) * 8];
#pragma unroll
        for (int m = 0; m < 4; ++m) acc3[m][j] = MFMA16(a[m], b, acc3[m][j]);
      }
      __syncthreads();
    }

    // epilogue: +bias, scatter with roll + RATIO re-interleave
    const int rr = wi >> 4, w1i = wi & 15;
#pragma unroll
    for (int j = 0; j < 3; ++j) {
      int c = wv * 48 + j * 16 + l15;
      float bias = bout[c];
#pragma unroll
      for (int m = 0; m < 4; ++m) {
#pragma unroll
        for (int r = 0; r < 4; ++r) {
          int pp = 16 * m + lg * 4 + r;
          if (pp < 49) {
            int i2 = pp / 7, j2 = pp - i2 * 7;
            int y = w1i * 7 + i2 + 3;  if (y >= 112) y -= 112;
            int xc = wj * 7 + j2 + 3;  if (xc >= 448) xc -= 448;
            out[(size_t)(y * 448 + xc) * 768 + rr * 192 + c] = acc3[m][j][r] + bias;
          }
        }
      }
    }
  }
}

extern "C" void kernel_launch(void* const* d_in, const int* in_sizes, int n_in,
                              void* d_out, int out_size, void* d_ws, size_t ws_size,
                              hipStream_t stream) {
  const float* x      = (const float*)d_in[0];
  const float* Wqkv   = (const float*)d_in[1];
  const float* bqkv   = (const float*)d_in[2];
  const float* relpos = (const float*)d_in[3];
  const float* Wout   = (const float*)d_in[4];
  const float* bout   = (const float*)d_in[5];
  float* out = (float*)d_out;
  wmsa_mfma<<<4096, 256, 0, stream>>>(x, Wqkv, bqkv, relpos, Wout, bout, out);
}

// Round 3
// 358.725 us; speedup vs baseline: 8.2731x; 1.6075x over previous
//
#include <hip/hip_runtime.h>

typedef _Float16 f16;
typedef _Float16 f16x8 __attribute__((ext_vector_type(8)));
typedef _Float16 f16x4 __attribute__((ext_vector_type(4)));
typedef float f32x4 __attribute__((ext_vector_type(4)));

#define MFMA16(a, b, c) __builtin_amdgcn_mfma_f32_16x16x32_f16(a, b, c, 0, 0, 0)

__device__ __forceinline__ f16x8 cvt8(const float* p) {
  const float4* s = (const float4*)p;
  float4 u0 = s[0], u1 = s[1];
  f16x8 v;
  v[0] = (f16)u0.x; v[1] = (f16)u0.y; v[2] = (f16)u0.z; v[3] = (f16)u0.w;
  v[4] = (f16)u1.x; v[5] = (f16)u1.y; v[6] = (f16)u1.z; v[7] = (f16)u1.w;
  return v;
}

// ---- prep: convert W_qkv / W_out to f16 fragment-linear layout in ws ----
// frag (kc, nt, lane l): n = nt*16 + (l&15), k = kc*32 + (l>>4)*8 .. +8
// stored at ws + fb*512 + l*8  (fb = kc*36+nt for qkv; 110592 + (kc*12+nt)*512 for out)
__global__ void wmsa_prep(const float* __restrict__ Wqkv,
                          const float* __restrict__ Wout,
                          f16* __restrict__ ws) {
  int gid = blockIdx.x * 256 + threadIdx.x;
  if (gid < 13824) {
    int fb = gid >> 6, l = gid & 63;
    int kc = fb / 36, nt = fb - kc * 36;
    int n = nt * 16 + (l & 15), k = kc * 32 + (l >> 4) * 8;
    *(f16x8*)(ws + (size_t)gid * 8) = cvt8(Wqkv + (size_t)n * 192 + k);
  } else if (gid < 18432) {
    int g2 = gid - 13824;
    int fb = g2 >> 6, l = g2 & 63;
    int kc = fb / 12, nt = fb - kc * 12;
    int n = nt * 16 + (l & 15), k = kc * 32 + (l >> 4) * 8;
    *(f16x8*)(ws + 110592 + (size_t)g2 * 8) = cvt8(Wout + (size_t)n * 192 + k);
  }
}

template <bool USE_WS>
__device__ __forceinline__ f16x8 load_bq(const f16* wsq, const float* Wqkv,
                                         int kc, int nt, int l) {
  if constexpr (USE_WS) {
    return *(const f16x8*)(wsq + (size_t)(kc * 36 + nt) * 512 + l * 8);
  } else {
    int n = nt * 16 + (l & 15), k = kc * 32 + (l >> 4) * 8;
    return cvt8(Wqkv + (size_t)n * 192 + k);
  }
}

template <bool USE_WS>
__device__ __forceinline__ f16x8 load_bo(const f16* wsq, const float* Wout,
                                         int kc, int nt, int l) {
  if constexpr (USE_WS) {
    return *(const f16x8*)(wsq + 110592 + (size_t)(kc * 12 + nt) * 512 + l * 8);
  } else {
    int n = nt * 16 + (l & 15), k = kc * 32 + (l >> 4) * 8;
    return cvt8(Wout + (size_t)n * 192 + k);
  }
}

// One block per 7x7 window, 512 threads = 8 waves, 2 waves/SIMD.
// Only 3 __syncthreads per block.
template <bool USE_WS>
__global__ __launch_bounds__(512, 1) void wmsa_main(
    const float* __restrict__ x,
    const float* __restrict__ Wqkv,
    const float* __restrict__ bqkv,
    const float* __restrict__ relpos,
    const float* __restrict__ Wout,
    const float* __restrict__ bout,
    const f16* __restrict__ ws,
    float* __restrict__ out)
{
  __shared__ __align__(16) f16 s_x[1536 * 8];      // input x -> attn out [64][24g] 24576 B
  __shared__ __align__(16) f16 s_qk[2 * 1536 * 8]; // q, k [64][24g]                49152 B
  __shared__ __align__(16) f16 s_vT[1536 * 8];     // v^T [192ch][8g]               24576 B
  __shared__ __align__(16) f16 s_p[2 * 512 * 8];   // P transpose, per head-group   16384 B
  __shared__ float s_add[6 * 169];                 //                                4056 B

  const int tid = threadIdx.x;
  const int wi = blockIdx.x >> 6, wj = blockIdx.x & 63;
  const int wv = tid >> 6;
  const int l = tid & 63;
  const int l15 = l & 15, lg = l >> 4;
  const f32x4 zero4 = {0.f, 0.f, 0.f, 0.f};

  // ---------------- Phase 0: stage rolled x window (f16, swizzled) ----------
  for (int i = tid; i < 6 * 169; i += 512) {
    int rem = i % 169;
    int di = rem / 13 - 6, dj = rem % 13 - 6;
    s_add[i] = relpos[i] + __expf((float)(di * di + dj * dj) * (-9.0f / 98.0f));
  }
  for (int gid = tid; gid < 1536; gid += 512) {
    int t = gid / 24, g = gid - t * 24;
    f16x8 v;
    if (t < 49) {
      int hh = wi * 7 + t / 7 + 3; if (hh >= 448) hh -= 448;
      int ww = wj * 7 + t % 7 + 3; if (ww >= 448) ww -= 448;
      v = cvt8(x + (size_t)(hh * 448 + ww) * 192 + g * 8);
    } else {
#pragma unroll
      for (int e = 0; e < 8; ++e) v[e] = (f16)0.0f;
    }
    *(f16x8*)&s_x[(t * 24 + (g ^ (t & 7))) * 8] = v;
  }
  __syncthreads();

  // ---------------- Phase 1: QKV GEMM, wave = (m-pair, 9 n-tiles) -----------
  {
    const int mp = wv >> 2, nr = wv & 3;
    f32x4 acc[2][9];
#pragma unroll
    for (int m = 0; m < 2; ++m)
#pragma unroll
      for (int j = 0; j < 9; ++j) acc[m][j] = zero4;

#pragma unroll
    for (int kc = 0; kc < 6; ++kc) {
      f16x8 b[9];
#pragma unroll
      for (int j = 0; j < 9; ++j) b[j] = load_bq<USE_WS>(ws, Wqkv, kc, 9 * nr + j, l);
      f16x8 a[2];
#pragma unroll
      for (int m = 0; m < 2; ++m) {
        int row = 32 * mp + 16 * m + l15;
        a[m] = *(const f16x8*)&s_x[(row * 24 + ((kc * 4 + lg) ^ (row & 7))) * 8];
      }
#pragma unroll
      for (int j = 0; j < 9; ++j) {
        acc[0][j] = MFMA16(a[0], b[j], acc[0][j]);
        acc[1][j] = MFMA16(a[1], b[j], acc[1][j]);
      }
    }

    // epilogue: +bias -> q/k token-major, v transposed
#pragma unroll
    for (int j = 0; j < 9; ++j) {
      int c = (9 * nr + j) * 16 + l15;
      float bias = bqkv[c];
      int part = c / 192;
      int ch = c - part * 192;
#pragma unroll
      for (int m = 0; m < 2; ++m) {
        int row0 = 32 * mp + 16 * m + lg * 4;
        if (part < 2) {
#pragma unroll
          for (int r = 0; r < 4; ++r) {
            int row = row0 + r;
            s_qk[part * 12288 + (row * 24 + ((ch >> 3) ^ (row & 7))) * 8 + (ch & 7)] =
                (f16)(acc[m][j][r] + bias);
          }
        } else {
          f16x4 v;
#pragma unroll
          for (int r = 0; r < 4; ++r) v[r] = (f16)(acc[m][j][r] + bias);
          *(f16x4*)&s_vT[(ch * 8 + ((row0 >> 3) ^ (ch & 7))) * 8 + (row0 & 7)] = v;
        }
      }
    }
  }
  __syncthreads();

  // ---------------- Phase 2: attention, wave = (p-tile, head-group) ---------
  // NO barriers inside: s_p rows and s_x out-rows are wave-private.
  {
    const int pt = wv & 3, hg = wv >> 2;
    const float scale = 0.17677669529663687f;
    const int prow = 16 * pt + l15;
    const int pbase = 16 * pt + lg * 4;
#pragma unroll
    for (int hh = 0; hh < 3; ++hh) {
      int h = hg * 3 + hh;
      f16x8 aq = *(const f16x8*)&s_qk[(prow * 24 + ((h * 4 + lg) ^ (prow & 7))) * 8];
      f32x4 sc[4];
#pragma unroll
      for (int jq = 0; jq < 4; ++jq) {
        int krow = 16 * jq + l15;
        f16x8 bk = *(const f16x8*)&s_qk[12288 + (krow * 24 + ((h * 4 + lg) ^ (krow & 7))) * 8];
        sc[jq] = MFMA16(aq, bk, zero4);
      }
      float sv[4][4];
      float m_r[4] = {-3.0e38f, -3.0e38f, -3.0e38f, -3.0e38f};
#pragma unroll
      for (int jq = 0; jq < 4; ++jq) {
        int q = 16 * jq + l15;
        int qi = q / 7, qj = q - qi * 7;
#pragma unroll
        for (int r = 0; r < 4; ++r) {
          int pp = pbase + r;
          float s = -1.0e30f;
          if (q < 49 && pp < 49) {
            int pi = pp / 7, pj = pp - pi * 7;
            s = sc[jq][r] * scale + s_add[h * 169 + (pi - qi + 6) * 13 + (pj - qj + 6)];
            bool msk = ((wi == 63) && ((pi < 4) != (qi < 4))) ||
                       ((wj == 63) && ((pj < 4) != (qj < 4)));
            if (msk) s = -1.0e30f;
          }
          sv[jq][r] = s;
          m_r[r] = fmaxf(m_r[r], s);
        }
      }
#pragma unroll
      for (int r = 0; r < 4; ++r)
#pragma unroll
        for (int d = 1; d < 16; d <<= 1)
          m_r[r] = fmaxf(m_r[r], __shfl_xor(m_r[r], d));
      float sum[4] = {0.f, 0.f, 0.f, 0.f};
#pragma unroll
      for (int jq = 0; jq < 4; ++jq)
#pragma unroll
        for (int r = 0; r < 4; ++r) {
          float e = __expf(sv[jq][r] - m_r[r]);
          sv[jq][r] = e;
          sum[r] += e;
        }
#pragma unroll
      for (int r = 0; r < 4; ++r) {
#pragma unroll
        for (int d = 1; d < 16; d <<= 1) sum[r] += __shfl_xor(sum[r], d);
        sum[r] = 1.0f / sum[r];
      }
#pragma unroll
      for (int jq = 0; jq < 4; ++jq) {
        int q = 16 * jq + l15;
#pragma unroll
        for (int r = 0; r < 4; ++r) {
          int row = pbase + r;
          s_p[hg * 4096 + (row * 8 + ((q >> 3) ^ (row & 7))) * 8 + (q & 7)] =
              (f16)(sv[jq][r] * sum[r]);
        }
      }
      // PV
      f32x4 o[2] = {zero4, zero4};
#pragma unroll
      for (int kq = 0; kq < 2; ++kq) {
        f16x8 ap = *(const f16x8*)&s_p[hg * 4096 + (prow * 8 + ((kq * 4 + lg) ^ (prow & 7))) * 8];
#pragma unroll
        for (int jn = 0; jn < 2; ++jn) {
          int ch = h * 32 + jn * 16 + l15;
          f16x8 bv = *(const f16x8*)&s_vT[(ch * 8 + ((kq * 4 + lg) ^ (ch & 7))) * 8];
          o[jn] = MFMA16(ap, bv, o[jn]);
        }
      }
#pragma unroll
      for (int jn = 0; jn < 2; ++jn) {
        int ch = h * 32 + jn * 16 + l15;
#pragma unroll
        for (int r = 0; r < 4; ++r) {
          int row = pbase + r;
          s_x[(row * 24 + ((ch >> 3) ^ (row & 7))) * 8 + (ch & 7)] = (f16)o[jn][r];
        }
      }
    }
  }
  __syncthreads();

  // ---------------- Phase 3: out-proj, wave = (m-pair, 3 n-tiles) -----------
  {
    const int mp = wv >> 2, q3 = wv & 3;
    f32x4 acc3[2][3];
#pragma unroll
    for (int m = 0; m < 2; ++m)
#pragma unroll
      for (int j = 0; j < 3; ++j) acc3[m][j] = zero4;

#pragma unroll
    for (int kc = 0; kc < 6; ++kc) {
      f16x8 b[3];
#pragma unroll
      for (int j = 0; j < 3; ++j) b[j] = load_bo<USE_WS>(ws, Wout, kc, 3 * q3 + j, l);
      f16x8 a[2];
#pragma unroll
      for (int m = 0; m < 2; ++m) {
        int row = 32 * mp + 16 * m + l15;
        a[m] = *(const f16x8*)&s_x[(row * 24 + ((kc * 4 + lg) ^ (row & 7))) * 8];
      }
#pragma unroll
      for (int j = 0; j < 3; ++j) {
        acc3[0][j] = MFMA16(a[0], b[j], acc3[0][j]);
        acc3[1][j] = MFMA16(a[1], b[j], acc3[1][j]);
      }
    }

    const int rr = wi >> 4, w1i = wi & 15;
#pragma unroll
    for (int j = 0; j < 3; ++j) {
      int c = (3 * q3 + j) * 16 + l15;
      float bias = bout[c];
#pragma unroll
      for (int m = 0; m < 2; ++m) {
#pragma unroll
        for (int r = 0; r < 4; ++r) {
          int pp = 32 * mp + 16 * m + lg * 4 + r;
          if (pp < 49) {
            int i2 = pp / 7, j2 = pp - i2 * 7;
            int y = w1i * 7 + i2 + 3;  if (y >= 112) y -= 112;
            int xc = wj * 7 + j2 + 3;  if (xc >= 448) xc -= 448;
            out[(size_t)(y * 448 + xc) * 768 + rr * 192 + c] = acc3[m][j][r] + bias;
          }
        }
      }
    }
  }
}

extern "C" void kernel_launch(void* const* d_in, const int* in_sizes, int n_in,
                              void* d_out, int out_size, void* d_ws, size_t ws_size,
                              hipStream_t stream) {
  const float* x      = (const float*)d_in[0];
  const float* Wqkv   = (const float*)d_in[1];
  const float* bqkv   = (const float*)d_in[2];
  const float* relpos = (const float*)d_in[3];
  const float* Wout   = (const float*)d_in[4];
  const float* bout   = (const float*)d_in[5];
  float* out = (float*)d_out;
  f16* ws = (f16*)d_ws;

  if (ws_size >= (size_t)(110592 + 36864) * sizeof(f16)) {
    wmsa_prep<<<72, 256, 0, stream>>>(Wqkv, Wout, ws);
    wmsa_main<true><<<4096, 512, 0, stream>>>(x, Wqkv, bqkv, relpos, Wout, bout, ws, out);
  } else {
    wmsa_main<false><<<4096, 512, 0, stream>>>(x, Wqkv, bqkv, relpos, Wout, bout, ws, out);
  }
}